// Round 3
// baseline (858.007 us; speedup 1.0000x reference)
//
#include <hip/hip_runtime.h>
#include <stdint.h>

// CTC forward loss, B=512, T=1024, C=256, L=64, S=129, blank=C-1.
// One wave (64 lanes) per batch element. Lane i holds alpha[2i], alpha[2i+1];
// lane 63 additionally alpha[128]. Cross-state deps via one __shfl_up.
//
// R2-R4 history: all global_load_lds staging variants (per-step vmcnt(31),
// asm-invisible gathers, 32-row chunked double-buffer with one vmcnt per 32
// steps) landed at 799-809us = 1894 cyc per 1KB row = one loaded HBM latency
// per row. Per-wave in-flight data stuck at ~1KB: 2 waves/CU x 1KB / 789ns
// x 256 CU = 664 GB/s == measured 672 GB/s. Conclusion: a wave's LDS-DMA
// ops do not pipeline against each other; issuing 32 does not create 32KB
// in flight.
//
// R5 change: drop LDS-DMA (and LDS) entirely. The gather indices (lab,
// BLANK) are alpha-independent, so gather y_pred[t][lab] / y_pred[t][BLANK]
// straight from global memory into rotating REGISTER chunk buffers (16
// steps per chunk, double-buffered A/B, fully unrolled -> static indices,
// registers not scratch). Plain global_load to VGPRs pipelines deeply per
// wave (vmcnt tracked by the compiler); loads for chunk k+1 issue before
// computing chunk k, so ~16 updates (~1600 cyc) hide the ~900 cyc loaded
// latency. HBM traffic unchanged (labels touch ~98% of 64B lines per row).

#define EPS 1e-7f
#define NEG -1e30f

constexpr int Bb = 512;
constexpr int Tt = 1024;
constexpr int Cc = 256;
constexpr int Ll = 64;
constexpr int BLANK = Cc - 1;
constexpr int CH = 16;       // steps per register chunk
constexpr int NCH = Tt / CH; // 64 chunks

__global__ __launch_bounds__(64, 1) void ctc_fwd_kernel(
    const int* __restrict__ y_true,   // [B, L] int32
    const float* __restrict__ y_pred, // [B, T, C] float32 probabilities
    float* __restrict__ out)          // [B] float32
{
    const int b = blockIdx.x;
    const int lane = threadIdx.x; // 0..63

    const float* __restrict__ row0 = y_pred + (size_t)b * Tt * Cc;

    // Label for odd state 2*lane+1.
    const int lab = y_true[b * Ll + lane];
    const int lab_prev = __shfl_up(lab, 1);
    const bool allow = (lane == 0) ? true : (lab != lab_prev);

    // Register chunk buffers (fully static indexing -> VGPRs, no scratch).
    float glA[CH], gbA[CH], glB[CH], gbB[CH];

    // Issue CH gather loads for chunk K into GL/GB. gb is wave-uniform
    // (BLANK index) -> compiler may scalarize; gl is a 16-line scatter.
#define LOAD_CHUNK(GL, GB, K)                                   \
    _Pragma("unroll") for (int r = 0; r < CH; ++r) {            \
        const int t = (K) * CH + r;                             \
        GL[r] = row0[t * Cc + lab];                             \
        GB[r] = row0[t * Cc + BLANK];                           \
    }

    LOAD_CHUNK(glA, gbA, 0)
    LOAD_CHUNK(glB, gbB, 1)

    // ---- t = 0 init ----
    float ae = (lane == 0) ? __logf(gbA[0] + EPS) : NEG; // alpha[2i]
    float ao = (lane == 0) ? __logf(glA[0] + EPS) : NEG; // alpha[2i+1]
    float a128 = NEG;                                    // alpha[128]

    auto update = [&](float gl, float gb) {
        const float lpl = __logf(gl + EPS);
        const float lpb = __logf(gb + EPS);
        float ao_up = __shfl_up(ao, 1);
        if (lane == 0) ao_up = NEG;

        // even state s=2i: from alpha[2i], alpha[2i-1]; emits blank
        const float m2 = fmaxf(ae, ao_up);
        const float ne =
            m2 + __logf(__expf(ae - m2) + __expf(ao_up - m2)) + lpb;

        // odd state s=2i+1: from alpha[2i+1], alpha[2i], (allow) alpha[2i-1]
        const float a3 = allow ? ao_up : NEG;
        const float m3 = fmaxf(fmaxf(ao, ae), a3);
        const float no =
            m3 +
            __logf(__expf(ao - m3) + __expf(ae - m3) + __expf(a3 - m3)) +
            lpl;

        // state 128 (lane 63): from alpha[128], alpha[127]; emits blank
        const float m1 = fmaxf(a128, ao);
        const float n128 =
            m1 + __logf(__expf(a128 - m1) + __expf(ao - m1)) + lpb;

        ae = ne;
        ao = no;
        a128 = n128;
    };

    // ---- chunk 0: steps t = 1..15 from A ----
#pragma unroll
    for (int r = 1; r < CH; ++r) update(glA[r], gbA[r]);

    // ---- chunks 1..62 in pairs; chunk k+1 loads issue before chunk k's
    // compute (prefetch distance = 16 updates ~ 1600 cyc) ----
    for (int k = 1; k + 1 < NCH; k += 2) {
        LOAD_CHUNK(glA, gbA, k + 1) // A held chunk k-1 (consumed)
#pragma unroll
        for (int r = 0; r < CH; ++r) update(glB[r], gbB[r]); // chunk k
        LOAD_CHUNK(glB, gbB, k + 2) // B consumed
#pragma unroll
        for (int r = 0; r < CH; ++r) update(glA[r], gbA[r]); // chunk k+1
    }
    // ---- tail: chunk 63 from B (steps 1008..1023) ----
#pragma unroll
    for (int r = 0; r < CH; ++r) update(glB[r], gbB[r]);

    // sequence ends on final blank (state 128) or final label (state 127)
    if (lane == 63) {
        const float m = fmaxf(a128, ao);
        out[b] = -(m + __logf(__expf(a128 - m) + __expf(ao - m)));
    }
}

extern "C" void kernel_launch(void* const* d_in, const int* in_sizes, int n_in,
                              void* d_out, int out_size, void* d_ws,
                              size_t ws_size, hipStream_t stream) {
    const int* y_true = (const int*)d_in[0];     // [512,64] int32
    const float* y_pred = (const float*)d_in[1]; // [512,1024,256] fp32
    float* out = (float*)d_out;                  // [512] fp32

    ctc_fwd_kernel<<<dim3(Bb), dim3(64), 0, stream>>>(y_true, y_pred, out);
}

// Round 4
// 797.084 us; speedup vs baseline: 1.0764x; 1.0764x over previous
//
#include <hip/hip_runtime.h>
#include <stdint.h>

// CTC forward loss, B=512, T=1024, C=256, L=64, S=129, blank=C-1.
// One wave (64 lanes) per batch element. Lane i holds alpha[2i], alpha[2i+1];
// lane 63 additionally alpha[128]. Cross-state deps via one __shfl_up.
//
// R5 discovery: bench dur_us is floored by ~500us of harness re-poison fills;
// the kernel itself was 344us with VGPR_Count=28 -> the compiler SANK all
// chunk-gather loads to just before their use (minimizing live ranges),
// destroying the software prefetch: each update paid a dependent ~600cyc
// loaded latency (807 cyc/step measured).
//
// R6 change: pin the prefetch. __builtin_amdgcn_sched_barrier(0) immediately
// after each LOAD_CHUNK forbids any instruction (i.e. the 32 gather loads)
// from moving across it, so chunk k+1's loads issue BEFORE chunk k's 16
// updates (~1400 cyc) and their auto-inserted waitcnt at first use is free.
// Expected signature of success: VGPR_Count jumps to ~100+, kernel ~<140us.

#define EPS 1e-7f
#define NEG -1e30f

constexpr int Bb = 512;
constexpr int Tt = 1024;
constexpr int Cc = 256;
constexpr int Ll = 64;
constexpr int BLANK = Cc - 1;
constexpr int CH = 16;       // steps per register chunk
constexpr int NCH = Tt / CH; // 64 chunks

__global__ __launch_bounds__(64, 1) void ctc_fwd_kernel(
    const int* __restrict__ y_true,   // [B, L] int32
    const float* __restrict__ y_pred, // [B, T, C] float32 probabilities
    float* __restrict__ out)          // [B] float32
{
    const int b = blockIdx.x;
    const int lane = threadIdx.x; // 0..63

    const float* __restrict__ row0 = y_pred + (size_t)b * Tt * Cc;

    // Label for odd state 2*lane+1.
    const int lab = y_true[b * Ll + lane];
    const int lab_prev = __shfl_up(lab, 1);
    const bool allow = (lane == 0) ? true : (lab != lab_prev);

    // Register chunk buffers (fully static indexing -> VGPRs, no scratch).
    float glA[CH], gbA[CH], glB[CH], gbB[CH];

    // Issue CH gather loads for chunk K into GL/GB, then pin them in place:
    // sched_barrier(0) forbids the scheduler from sinking the loads toward
    // their consumers (which is what produced R5's 807 cyc/step).
#define LOAD_CHUNK(GL, GB, K)                                   \
    do {                                                        \
        _Pragma("unroll") for (int r = 0; r < CH; ++r) {        \
            const int t = (K) * CH + r;                         \
            GL[r] = row0[t * Cc + lab];                         \
            GB[r] = row0[t * Cc + BLANK];                       \
        }                                                       \
        __builtin_amdgcn_sched_barrier(0);                      \
    } while (0)

    LOAD_CHUNK(glA, gbA, 0);
    LOAD_CHUNK(glB, gbB, 1);

    // ---- t = 0 init ----
    float ae = (lane == 0) ? __logf(gbA[0] + EPS) : NEG; // alpha[2i]
    float ao = (lane == 0) ? __logf(glA[0] + EPS) : NEG; // alpha[2i+1]
    float a128 = NEG;                                    // alpha[128]

    auto update = [&](float gl, float gb) {
        const float lpl = __logf(gl + EPS);
        const float lpb = __logf(gb + EPS);
        float ao_up = __shfl_up(ao, 1);
        if (lane == 0) ao_up = NEG;

        // even state s=2i: from alpha[2i], alpha[2i-1]; emits blank
        const float m2 = fmaxf(ae, ao_up);
        const float ne =
            m2 + __logf(__expf(ae - m2) + __expf(ao_up - m2)) + lpb;

        // odd state s=2i+1: from alpha[2i+1], alpha[2i], (allow) alpha[2i-1]
        const float a3 = allow ? ao_up : NEG;
        const float m3 = fmaxf(fmaxf(ao, ae), a3);
        const float no =
            m3 +
            __logf(__expf(ao - m3) + __expf(ae - m3) + __expf(a3 - m3)) +
            lpl;

        // state 128 (lane 63): from alpha[128], alpha[127]; emits blank
        const float m1 = fmaxf(a128, ao);
        const float n128 =
            m1 + __logf(__expf(a128 - m1) + __expf(ao - m1)) + lpb;

        ae = ne;
        ao = no;
        a128 = n128;
    };

    // ---- chunk 0: steps t = 1..15 from A ----
#pragma unroll
    for (int r = 1; r < CH; ++r) update(glA[r], gbA[r]);

    // ---- chunks 1..62 in pairs; chunk k+1's loads are pinned before
    // chunk k's 16 updates (~1400 cyc prefetch distance) ----
    for (int k = 1; k + 1 < NCH; k += 2) {
        LOAD_CHUNK(glA, gbA, k + 1); // A held chunk k-1 (consumed)
#pragma unroll
        for (int r = 0; r < CH; ++r) update(glB[r], gbB[r]); // chunk k
        LOAD_CHUNK(glB, gbB, k + 2); // B consumed
#pragma unroll
        for (int r = 0; r < CH; ++r) update(glA[r], gbA[r]); // chunk k+1
    }
    // ---- tail: chunk 63 from B (steps 1008..1023) ----
#pragma unroll
    for (int r = 0; r < CH; ++r) update(glB[r], gbB[r]);

    // sequence ends on final blank (state 128) or final label (state 127)
    if (lane == 63) {
        const float m = fmaxf(a128, ao);
        out[b] = -(m + __logf(__expf(a128 - m) + __expf(ao - m)));
    }
}

extern "C" void kernel_launch(void* const* d_in, const int* in_sizes, int n_in,
                              void* d_out, int out_size, void* d_ws,
                              size_t ws_size, hipStream_t stream) {
    const int* y_true = (const int*)d_in[0];     // [512,64] int32
    const float* y_pred = (const float*)d_in[1]; // [512,1024,256] fp32
    float* out = (float*)d_out;                  // [512] fp32

    ctc_fwd_kernel<<<dim3(Bb), dim3(64), 0, stream>>>(y_true, y_pred, out);
}

// Round 6
// 779.905 us; speedup vs baseline: 1.1001x; 1.0220x over previous
//
#include <hip/hip_runtime.h>
#include <stdint.h>

// CTC forward loss, B=512, T=1024, C=256, L=64, S=129, blank=C-1.
// One wave (64 lanes) per batch element. Lane i holds alpha[2i], alpha[2i+1];
// lane 63 additionally alpha[128].
//
// R5/R6 history: bench dur_us = ~514us harness fills + kernel. Reg-chunk
// gather + sched_barrier prefetch pin got the kernel to ~283us = 664
// cyc/step. All staging structures converge there -> the per-step SERIAL
// chain is the limiter (0.5 waves/SIMD, zero TLP): ds_bpermute shfl_up
// (~40-120cyc) + ln-domain logsumexp wrapper muls.
//
// R7 (compile-fix in R8): attack the chain.
//  1. shfl_up(ao,1) -> DPP wave_shr:1 (VALU pipe, ~8cyc); old=NEG makes
//     lane0's boundary value fall out of the DPP directly.
//  2. log2 domain throughout via __builtin_exp2f/__builtin_log2f (clang
//     lowers llvm.exp2/log2.f32 to single v_exp_f32/v_log_f32 -- the HIP
//     __expf/__logf wrappers add a v_mul per call on the chain). Track
//     alpha in log2 units, scale by ln2 once at the end.
//     (R7's __exp2f/__log2f names collided with glibc math.h internals.)
// Chain estimate drops ~160-180 -> ~50 cyc/step; memory gather throughput
// (~200 cyc/step at 2 waves/CU) becomes the limiter.

#define EPS 1e-7f
#define NEG -1e30f
#define LN2 0.69314718055994530942f

constexpr int Bb = 512;
constexpr int Tt = 1024;
constexpr int Cc = 256;
constexpr int Ll = 64;
constexpr int BLANK = Cc - 1;
constexpr int CH = 16;       // steps per register chunk
constexpr int NCH = Tt / CH; // 64 chunks

#define EXP2(x) __builtin_exp2f(x)
#define LOG2(x) __builtin_log2f(x)

// lane i gets x from lane i-1; lane 0 gets NEG. DPP wave_shr:1 (0x138),
// row_mask=bank_mask=0xF (all lanes written), bound_ctrl=false (invalid
// source lane -> old operand = NEG).
__device__ __forceinline__ float dpp_shr1_neg(float x) {
    const int r = __builtin_amdgcn_update_dpp(
        __float_as_int(NEG), __float_as_int(x), 0x138, 0xF, 0xF, false);
    return __int_as_float(r);
}

__global__ __launch_bounds__(64, 1) void ctc_fwd_kernel(
    const int* __restrict__ y_true,   // [B, L] int32
    const float* __restrict__ y_pred, // [B, T, C] float32 probabilities
    float* __restrict__ out)          // [B] float32
{
    const int b = blockIdx.x;
    const int lane = threadIdx.x; // 0..63

    const float* __restrict__ row0 = y_pred + (size_t)b * Tt * Cc;

    // Label for odd state 2*lane+1.
    const int lab = y_true[b * Ll + lane];
    const int lab_prev = __shfl_up(lab, 1);
    const bool allow = (lane == 0) ? true : (lab != lab_prev);

    // Register chunk buffers (fully static indexing -> VGPRs, no scratch).
    float glA[CH], gbA[CH], glB[CH], gbB[CH];

    // Issue CH gather loads for chunk K, then pin them with sched_barrier(0)
    // so the scheduler cannot sink them toward their consumers (R5 lesson:
    // sinking cost ~600 cyc dependent latency per step).
#define LOAD_CHUNK(GL, GB, K)                                   \
    do {                                                        \
        _Pragma("unroll") for (int r = 0; r < CH; ++r) {        \
            const int t = (K) * CH + r;                         \
            GL[r] = row0[t * Cc + lab];                         \
            GB[r] = row0[t * Cc + BLANK];                       \
        }                                                       \
        __builtin_amdgcn_sched_barrier(0);                      \
    } while (0)

    LOAD_CHUNK(glA, gbA, 0);
    LOAD_CHUNK(glB, gbB, 1);

    // ---- t = 0 init (log2 domain) ----
    float ae = (lane == 0) ? LOG2(gbA[0] + EPS) : NEG; // alpha[2i]
    float ao = (lane == 0) ? LOG2(glA[0] + EPS) : NEG; // alpha[2i+1]
    float a128 = NEG;                                  // alpha[128]

    auto update = [&](float gl, float gb) {
        // lp2* are independent of alpha: scheduler can hoist them into
        // stall shadows.
        const float lpl = LOG2(gl + EPS);
        const float lpb = LOG2(gb + EPS);
        const float ao_up = dpp_shr1_neg(ao); // lane0 -> NEG via DPP old

        // even state s=2i: from alpha[2i], alpha[2i-1]; emits blank
        const float m2 = fmaxf(ae, ao_up);
        const float ne =
            m2 + LOG2(EXP2(ae - m2) + EXP2(ao_up - m2)) + lpb;

        // odd state s=2i+1: from alpha[2i+1], alpha[2i], (allow) alpha[2i-1]
        const float a3 = allow ? ao_up : NEG;
        const float m3 = fmaxf(fmaxf(ao, ae), a3); // -> v_max3_f32
        const float no =
            m3 + LOG2(EXP2(ao - m3) + EXP2(ae - m3) + EXP2(a3 - m3)) + lpl;

        // state 128 (lane 63): from alpha[128], alpha[127]; emits blank
        const float m1 = fmaxf(a128, ao);
        const float n128 =
            m1 + LOG2(EXP2(a128 - m1) + EXP2(ao - m1)) + lpb;

        ae = ne;
        ao = no;
        a128 = n128;
    };

    // ---- chunk 0: steps t = 1..15 from A ----
#pragma unroll
    for (int r = 1; r < CH; ++r) update(glA[r], gbA[r]);

    // ---- chunks 1..62 in pairs; chunk k+1's loads pinned before chunk k's
    // 16 updates ----
    for (int k = 1; k + 1 < NCH; k += 2) {
        LOAD_CHUNK(glA, gbA, k + 1); // A held chunk k-1 (consumed)
#pragma unroll
        for (int r = 0; r < CH; ++r) update(glB[r], gbB[r]); // chunk k
        LOAD_CHUNK(glB, gbB, k + 2); // B consumed
#pragma unroll
        for (int r = 0; r < CH; ++r) update(glA[r], gbA[r]); // chunk k+1
    }
    // ---- tail: chunk 63 from B (steps 1008..1023) ----
#pragma unroll
    for (int r = 0; r < CH; ++r) update(glB[r], gbB[r]);

    // sequence ends on final blank (state 128) or final label (state 127);
    // scale log2 -> ln once.
    if (lane == 63) {
        const float m = fmaxf(a128, ao);
        out[b] = -LN2 * (m + LOG2(EXP2(a128 - m) + EXP2(ao - m)));
    }
}

extern "C" void kernel_launch(void* const* d_in, const int* in_sizes, int n_in,
                              void* d_out, int out_size, void* d_ws,
                              size_t ws_size, hipStream_t stream) {
    const int* y_true = (const int*)d_in[0];     // [512,64] int32
    const float* y_pred = (const float*)d_in[1]; // [512,1024,256] fp32
    float* out = (float*)d_out;                  // [512] fp32

    ctc_fwd_kernel<<<dim3(Bb), dim3(64), 0, stream>>>(y_true, y_pred, out);
}